// Round 26
// baseline (165.090 us; speedup 1.0000x reference)
//
#include <hip/hip_runtime.h>
#include <stdint.h>

typedef __bf16 bf16x8 __attribute__((ext_vector_type(8)));
typedef float f32x4 __attribute__((ext_vector_type(4)));
typedef unsigned short u16;
typedef const __attribute__((address_space(1))) void* as1_cvp;
typedef __attribute__((address_space(3))) void* as3_vp;

__device__ __forceinline__ u16 f2bf(float f) {
  union { float f; unsigned u; } v; v.f = f;
  unsigned r = v.u + 0x7fffu + ((v.u >> 16) & 1u);
  return (u16)(r >> 16);
}

// ---- hist + stable counting-sort perm + tile maps (single block's work) ----
__device__ void hist_body(const int* __restrict__ idx, int n,
                          int* __restrict__ starts, int* __restrict__ perm,
                          int* __restrict__ tmap64,
                          int* cnt /* [4][256] shared */, int* gmeta /* [8] */) {
  int (*c4)[256] = (int(*)[256])cnt;
  int* gtot = gmeta;
  int* gstart = gmeta + 4;
  const int t = threadIdx.x;
  const int rpt = (n + 255) >> 8;
  const int base = t * rpt;
  int c[4] = {0, 0, 0, 0};
  for (int j = 0; j < rpt; ++j) {
    const int i = base + j;
    if (i < n) c[idx[i] & 3]++;
  }
  #pragma unroll
  for (int g = 0; g < 4; ++g) c4[g][t] = c[g];
  __syncthreads();
  const int w = t >> 6, l = t & 63;
  {
    const int s0 = c4[w][l * 4 + 0], s1 = c4[w][l * 4 + 1];
    const int s2 = c4[w][l * 4 + 2], s3 = c4[w][l * 4 + 3];
    const int sum = s0 + s1 + s2 + s3;
    int sc = sum;
    #pragma unroll
    for (int d = 1; d < 64; d <<= 1) {
      const int o = __shfl_up(sc, d, 64);
      if (l >= d) sc += o;
    }
    const int ex = sc - sum;
    c4[w][l * 4 + 0] = ex;
    c4[w][l * 4 + 1] = ex + s0;
    c4[w][l * 4 + 2] = ex + s0 + s1;
    c4[w][l * 4 + 3] = ex + s0 + s1 + s2;
    if (l == 63) gtot[w] = sc;
  }
  __syncthreads();
  if (t == 0) {
    int s = 0, nt64 = 0;
    for (int g = 0; g < 4; ++g) {
      gstart[g] = s;
      starts[g] = s;
      const int cg = gtot[g];
      for (int j = 0; j < cg; j += 64) tmap64[nt64++] = (g << 28) | (s + j);
      s += cg;
    }
    starts[4] = s;
    while (nt64 < 40) tmap64[nt64++] = -1;
  }
  __syncthreads();
  int run[4] = {0, 0, 0, 0};
  for (int j = 0; j < rpt; ++j) {
    const int i = base + j;
    if (i < n) {
      const int g = idx[i] & 3;
      perm[gstart[g] + c4[g][t] + run[g]] = i;
      run[g]++;
    }
  }
}

// ---- shared transpose body: W [K][N] f32 tile -> WT [N][K] bf16 ----
__device__ __forceinline__ void wtrans_body(
    float (*tile)[65], const float* __restrict__ W, u16* __restrict__ WT,
    int K, int N, int tx, int ty, int o) {
  const float* Wo = W + (size_t)o * K * N;
  u16* WTo = WT + (size_t)o * N * K;
  const int k0 = ty * 64, n0 = tx * 64;
  const int rr = threadIdx.x >> 4, cc = threadIdx.x & 15;
  #pragma unroll
  for (int j = 0; j < 4; ++j) {
    const int r = j * 16 + rr;
    const float4 v = *(const float4*)(Wo + (size_t)(k0 + r) * N + n0 + cc * 4);
    tile[r][cc * 4 + 0] = v.x; tile[r][cc * 4 + 1] = v.y;
    tile[r][cc * 4 + 2] = v.z; tile[r][cc * 4 + 3] = v.w;
  }
  __syncthreads();
  #pragma unroll
  for (int j = 0; j < 4; ++j) {
    const int nrow = j * 16 + rr;
    ushort4 u;
    u.x = f2bf(tile[cc * 4 + 0][nrow]);
    u.y = f2bf(tile[cc * 4 + 1][nrow]);
    u.z = f2bf(tile[cc * 4 + 2][nrow]);
    u.w = f2bf(tile[cc * 4 + 3][nrow]);
    *(ushort4*)(WTo + (size_t)(n0 + nrow) * K + k0 + cc * 4) = u;
  }
}

// ---- k0: W1T transpose (blocks 0..2047) ∥ hist + counter-zero (block 2048) ----
__global__ __launch_bounds__(256) void w1t_hist_kernel(
    const float* __restrict__ W1, u16* __restrict__ W1T,
    const int* __restrict__ idx, int n, int* __restrict__ starts,
    int* __restrict__ perm, int* __restrict__ tmap64,
    int* __restrict__ pcnt) {
  __shared__ float tile[64][65];   // 16.9 KB, reused as hist scratch
  const int bid = blockIdx.x;
  if (bid == 2048) {  // hist hides under the 48 MB transpose
    for (int i = threadIdx.x; i < 320; i += 256) pcnt[i] = 0;  // split-K cnts
    hist_body(idx, n, starts, perm, tmap64,
              (int*)&tile[0][0], (int*)&tile[32][0]);
    return;
  }
  const int xcd = bid & 7, i = bid >> 3;
  const int tx = (xcd << 2) | (i & 3);   // consumer-XCD-affine (xcd = tx>>2)
  const int ty = (i >> 2) & 15;
  const int o = i >> 6;
  wtrans_body(tile, W1, W1T, 1024, 2048, tx, ty, o);
}

// ---- k1: gather + f32->bf16 convert into sorted order ----
__global__ __launch_bounds__(256) void gather_kernel(
    const float* __restrict__ x, const int* __restrict__ perm,
    u16* __restrict__ Xs) {
  const int p = blockIdx.x;
  const int b = perm[p];
  const float4 v = ((const float4*)(x + (size_t)b * 1024))[threadIdx.x];
  ushort4 u;
  u.x = f2bf(v.x); u.y = f2bf(v.y); u.z = f2bf(v.z); u.w = f2bf(v.w);
  ((ushort4*)(Xs + (size_t)p * 1024))[threadIdx.x] = u;
}

// ---- grouped GEMM body: tile TM x 128, BK=64, 4 waves, 2-buf LDS,
// counted vmcnt, T2 XOR swizzle, T5 setprio, XCD-chunked swizzle.
// EPI 0: bf16 out + bias (sorted order).
// EPI 1: split-K x2 with LAST-BLOCK reduction (wait-free): store my partial,
//   fence, count; the 2nd finisher reads the other partial, adds its own
//   (register-resident) + b2, scatter-writes out via perm. IEEE add is
//   commutative -> bitwise identical to the separate reduce pass.
template <int EPI, int TM, int NT_PAD, int KT, int NN, int NTN, int SPLIT>
__device__ __forceinline__ void gemm_body(
    char* smem, int bid,
    const u16* __restrict__ A, const u16* __restrict__ BT,
    const float* __restrict__ bias, const int* __restrict__ starts,
    const int* __restrict__ tmap, float* __restrict__ outP,
    u16* __restrict__ outH, const int* __restrict__ perm,
    float* __restrict__ outF, int* __restrict__ pcnt) {
  constexpr int MR = TM / 32;
  constexpr int ABUF = TM * 128;
  constexpr int BSTR = ABUF + 16384;

  const int nwg = NT_PAD * NTN * SPLIT;  // % 8 == 0
  const int q = nwg >> 3;
  const int swz = (bid & 7) * q + (bid >> 3);  // XCD-chunked bijective
  const int tile = swz % NT_PAD;               // m fastest: B-panel L2 reuse
  const int rest = swz / NT_PAD;
  const int n_t = rest % NTN;
  const int s = rest / NTN;

  const int tm = tmap[tile];
  if (tm < 0) return;
  const int o = tm >> 28;
  const int m_start = tm & 0x0FFFFFFF;
  const int g1 = starts[o + 1];
  const int n_start = n_t * 128;
  const int kb0 = s * (KT / SPLIT);
  const u16* Bo = BT + (size_t)o * NN * KT;

  const int tid = threadIdx.x;
  const int w = tid >> 6;
  const int l = tid & 63;
  const int wm = w >> 1, wn = w & 1;
  const int l8 = l & 7, ld8 = l >> 3;

  // T2: pre-swizzled global source; linear LDS dest holds swizzled layout
  const int src_unit = l8 ^ (ld8 & 7);

  const u16* pA[MR];
  #pragma unroll
  for (int j = 0; j < MR; ++j) {
    int r = m_start + (j * 4 + w) * 8 + ld8;
    if (r >= g1) r = g1 - 1;
    pA[j] = A + (size_t)r * KT + kb0 + src_unit * 8;
  }
  const u16* pB[4];
  #pragma unroll
  for (int j = 0; j < 4; ++j) {
    const int nr = n_start + (j * 4 + w) * 8 + ld8;
    pB[j] = Bo + (size_t)nr * KT + kb0 + src_unit * 8;
  }

#define STAGE(dst_off)                                                         \
  {                                                                            \
    _Pragma("unroll")                                                          \
    for (int j = 0; j < MR; ++j)                                               \
      __builtin_amdgcn_global_load_lds((as1_cvp)pA[j],                         \
          (as3_vp)(smem + (dst_off) + (j * 4 + w) * 1024), 16, 0, 0);          \
    _Pragma("unroll")                                                          \
    for (int j = 0; j < 4; ++j)                                                \
      __builtin_amdgcn_global_load_lds((as1_cvp)pB[j],                         \
          (as3_vp)(smem + (dst_off) + ABUF + (j * 4 + w) * 1024), 16, 0, 0);   \
    _Pragma("unroll") for (int j = 0; j < MR; ++j) pA[j] += 64;                \
    _Pragma("unroll") for (int j = 0; j < 4; ++j) pB[j] += 64;                 \
  }

  const int lrow = l & 15;
  const int lx = l & 7;
  const int lu = l >> 4;
  int offA[MR][2], offB[4][2];
  #pragma unroll
  for (int a = 0; a < MR; ++a)
    #pragma unroll
    for (int kk = 0; kk < 2; ++kk)
      offA[a][kk] = (wm * (TM / 2) + a * 16 + lrow) * 128 + (((kk * 4 + lu) ^ lx) << 4);
  #pragma unroll
  for (int b = 0; b < 4; ++b)
    #pragma unroll
    for (int kk = 0; kk < 2; ++kk)
      offB[b][kk] = (wn * 64 + b * 16 + lrow) * 128 + (((kk * 4 + lu) ^ lx) << 4);

  f32x4 acc[MR][4] = {};

  const int nK = (KT / SPLIT) >> 6;
  STAGE(0);
  for (int kt = 0; kt < nK; ++kt) {
    const int cur = (kt & 1) * BSTR;
    if (kt + 1 < nK) {
      STAGE(BSTR - cur);
      if constexpr (TM == 128)
        asm volatile("s_waitcnt vmcnt(8)" ::: "memory");
      else
        asm volatile("s_waitcnt vmcnt(6)" ::: "memory");
    } else {
      asm volatile("s_waitcnt vmcnt(0)" ::: "memory");
    }
    __builtin_amdgcn_s_barrier();

    bf16x8 af[MR][2], bfr[4][2];
    #pragma unroll
    for (int a = 0; a < MR; ++a)
      #pragma unroll
      for (int kk = 0; kk < 2; ++kk)
        af[a][kk] = *(const bf16x8*)(smem + cur + offA[a][kk]);
    #pragma unroll
    for (int b = 0; b < 4; ++b)
      #pragma unroll
      for (int kk = 0; kk < 2; ++kk)
        bfr[b][kk] = *(const bf16x8*)(smem + cur + ABUF + offB[b][kk]);
    asm volatile("s_waitcnt lgkmcnt(0)" ::: "memory");
    __builtin_amdgcn_s_barrier();

    __builtin_amdgcn_s_setprio(1);
    #pragma unroll
    for (int kk = 0; kk < 2; ++kk)
      #pragma unroll
      for (int a = 0; a < MR; ++a)
        #pragma unroll
        for (int b = 0; b < 4; ++b)
          acc[a][b] = __builtin_amdgcn_mfma_f32_16x16x32_bf16(af[a][kk], bfr[b][kk], acc[a][b], 0, 0, 0);
    __builtin_amdgcn_s_setprio(0);
  }
#undef STAGE

  // epilogue: C/D layout col = l&15, row = (l>>4)*4 + r  [m89-verified]
  const int col_l = l & 15;
  const int row_l = (l >> 4) << 2;
  if constexpr (EPI == 0) {
    #pragma unroll
    for (int a = 0; a < MR; ++a) {
      #pragma unroll
      for (int b = 0; b < 4; ++b) {
        const int n = n_start + wn * 64 + b * 16 + col_l;
        const float bv = bias[n];
        #pragma unroll
        for (int r = 0; r < 4; ++r) {
          const int p = m_start + wm * (TM / 2) + a * 16 + row_l + r;
          if (p < g1) outH[(size_t)p * NN + n] = f2bf(acc[a][b][r] + bv);
        }
      }
    }
  } else {
    // 1) store my partial
    #pragma unroll
    for (int a = 0; a < MR; ++a) {
      #pragma unroll
      for (int b = 0; b < 4; ++b) {
        const int n = n_start + wn * 64 + b * 16 + col_l;
        #pragma unroll
        for (int r = 0; r < 4; ++r) {
          const int p = m_start + wm * (TM / 2) + a * 16 + row_l + r;
          if (p < g1)
            outP[((size_t)(s * 2048 + p)) * NN + n] = acc[a][b][r];
        }
      }
    }
    // 2) release my stores, then count; 2nd finisher reduces (wait-free)
    __threadfence();
    __syncthreads();
    __shared__ int s_last;
    if (tid == 0)
      s_last = (atomicAdd(&pcnt[tile * NTN + n_t], 1) == 1);
    __syncthreads();
    if (s_last) {
      __threadfence();  // acquire: other split's partial now visible
      const size_t so = (size_t)((s ^ 1) * 2048);
      #pragma unroll
      for (int a = 0; a < MR; ++a) {
        #pragma unroll
        for (int b = 0; b < 4; ++b) {
          const int n = n_start + wn * 64 + b * 16 + col_l;
          const float bv = bias[n];
          #pragma unroll
          for (int r = 0; r < 4; ++r) {
            const int p = m_start + wm * (TM / 2) + a * 16 + row_l + r;
            if (p < g1)
              outF[(size_t)perm[p] * NN + n] =
                  (acc[a][b][r] + outP[(so + p) * NN + n]) + bv;
          }
        }
      }
    }
  }
}

// ---- k2: GEMM1 TM=64 wide-grid (blocks 0..639) ∥ W2T transpose (640..2687) ----
__global__ __launch_bounds__(256, 3) void gemm1_w2t_kernel(
    const u16* __restrict__ Xs, const u16* __restrict__ W1T,
    const float* __restrict__ b1, const int* __restrict__ starts,
    const int* __restrict__ tmap64, u16* __restrict__ Hs,
    const float* __restrict__ W2, u16* __restrict__ W2T) {
  __shared__ char smem[49152];
  const int bid = blockIdx.x;
  if (bid < 640) {
    gemm_body<0, 64, 40, 1024, 2048, 16, 1>(
        smem, bid, Xs, W1T, b1, starts, tmap64, nullptr, Hs,
        nullptr, nullptr, nullptr);
  } else {
    // W2: K=2048, N=1024; consumer-XCD-affine (xcd = tx>>1). 640%8==0 so
    // (bid-640)&7 preserves bid&7 XCD parity.
    const int b = bid - 640;
    const int xcd = b & 7, i = b >> 3;
    const int tx = (xcd << 1) | (i & 1);
    const int ty = (i >> 1) & 31;
    const int o = i >> 6;
    wtrans_body((float(*)[65])smem, W2, W2T, 2048, 1024, tx, ty, o);
  }
}

// ---- k3: GEMM2 split-K x2 with fused last-block reduce -> out ----
__global__ __launch_bounds__(256, 3) void gemm2s_kernel(
    const u16* __restrict__ Hs, const u16* __restrict__ W2T,
    const float* __restrict__ b2, const int* __restrict__ starts,
    const int* __restrict__ tmap64, float* __restrict__ part,
    const int* __restrict__ perm, float* __restrict__ out,
    int* __restrict__ pcnt) {
  __shared__ char smem[49152];
  gemm_body<1, 64, 40, 2048, 1024, 8, 2>(
      smem, blockIdx.x, Hs, W2T, b2, starts, tmap64, part, nullptr,
      perm, out, pcnt);
}

extern "C" void kernel_launch(void* const* d_in, const int* in_sizes, int n_in,
                              void* d_out, int out_size, void* d_ws, size_t ws_size,
                              hipStream_t stream) {
  (void)n_in; (void)out_size; (void)ws_size;
  const float* x   = (const float*)d_in[0];
  const int*   idx = (const int*)d_in[1];
  const float* W1  = (const float*)d_in[2];
  const float* b1  = (const float*)d_in[3];
  const float* W2  = (const float*)d_in[4];
  const float* b2  = (const float*)d_in[5];
  float* out = (float*)d_out;

  const int B = in_sizes[1];  // 2048

  // workspace layout (~44.06 MB; part aliases W1T, dead after GEMM1)
  char* ws = (char*)d_ws;
  u16* W1T     = (u16*)(ws);                    // 16 MB [o][N=2048][K=1024]
  float* part  = (float*)(ws);                  // 2*2048*1024 f32 = 16 MB alias
  u16* W2T     = (u16*)(ws + 16777216);         // 16 MB [o][N=1024][K=2048]
  u16* Xs      = (u16*)(ws + 33554432);         // B*1024 bf16 = 4 MB (sorted)
  u16* Hs      = (u16*)(ws + 37748736);         // B*2048 bf16 = 8 MB (sorted)
  int* perm    = (int*)(ws + 46137344);         // B ints
  int* starts  = (int*)(ws + 46137344 + 8192);  // 5 ints
  int* tmap64  = starts + 128;                  // 40 ints
  int* pcnt    = starts + 512;                  // 320 split-K pair counters

  // k0: W1T transpose ∥ hist + counter-zero (hides under 48 MB transpose)
  w1t_hist_kernel<<<2049, 256, 0, stream>>>(W1, W1T, idx, B, starts, perm,
                                            tmap64, pcnt);
  // k1: gather x rows into sorted bf16 Xs
  gather_kernel<<<B, 256, 0, stream>>>(x, perm, Xs);
  // k2: GEMM1 (TM=64, 640 blocks x 16 K-steps) ∥ W2T transpose
  gemm1_w2t_kernel<<<640 + 2048, 256, 0, stream>>>(
      Xs, W1T, b1, starts, tmap64, Hs, W2, W2T);
  // k3: GEMM2 split-K x2 + fused last-block reduce (deletes k4 pass + gap)
  gemm2s_kernel<<<640, 256, 0, stream>>>(Hs, W2T, b2, starts, tmap64, part,
                                         perm, out, pcnt);
}

// Round 27
// 66.123 us; speedup vs baseline: 2.4967x; 2.4967x over previous
//
#include <hip/hip_runtime.h>
#include <stdint.h>

typedef __bf16 bf16x8 __attribute__((ext_vector_type(8)));
typedef float f32x4 __attribute__((ext_vector_type(4)));
typedef unsigned short u16;
typedef const __attribute__((address_space(1))) void* as1_cvp;
typedef __attribute__((address_space(3))) void* as3_vp;

__device__ __forceinline__ u16 f2bf(float f) {
  union { float f; unsigned u; } v; v.f = f;
  unsigned r = v.u + 0x7fffu + ((v.u >> 16) & 1u);
  return (u16)(r >> 16);
}

// ---- hist + stable counting-sort perm + tile maps (single block's work) ----
__device__ void hist_body(const int* __restrict__ idx, int n,
                          int* __restrict__ starts, int* __restrict__ perm,
                          int* __restrict__ tmap64,
                          int* cnt /* [4][256] shared */, int* gmeta /* [8] */) {
  int (*c4)[256] = (int(*)[256])cnt;
  int* gtot = gmeta;
  int* gstart = gmeta + 4;
  const int t = threadIdx.x;
  const int rpt = (n + 255) >> 8;
  const int base = t * rpt;
  int c[4] = {0, 0, 0, 0};
  for (int j = 0; j < rpt; ++j) {
    const int i = base + j;
    if (i < n) c[idx[i] & 3]++;
  }
  #pragma unroll
  for (int g = 0; g < 4; ++g) c4[g][t] = c[g];
  __syncthreads();
  const int w = t >> 6, l = t & 63;
  {
    const int s0 = c4[w][l * 4 + 0], s1 = c4[w][l * 4 + 1];
    const int s2 = c4[w][l * 4 + 2], s3 = c4[w][l * 4 + 3];
    const int sum = s0 + s1 + s2 + s3;
    int sc = sum;
    #pragma unroll
    for (int d = 1; d < 64; d <<= 1) {
      const int o = __shfl_up(sc, d, 64);
      if (l >= d) sc += o;
    }
    const int ex = sc - sum;
    c4[w][l * 4 + 0] = ex;
    c4[w][l * 4 + 1] = ex + s0;
    c4[w][l * 4 + 2] = ex + s0 + s1;
    c4[w][l * 4 + 3] = ex + s0 + s1 + s2;
    if (l == 63) gtot[w] = sc;
  }
  __syncthreads();
  if (t == 0) {
    int s = 0, nt64 = 0;
    for (int g = 0; g < 4; ++g) {
      gstart[g] = s;
      starts[g] = s;
      const int cg = gtot[g];
      for (int j = 0; j < cg; j += 64) tmap64[nt64++] = (g << 28) | (s + j);
      s += cg;
    }
    starts[4] = s;
    while (nt64 < 40) tmap64[nt64++] = -1;
  }
  __syncthreads();
  int run[4] = {0, 0, 0, 0};
  for (int j = 0; j < rpt; ++j) {
    const int i = base + j;
    if (i < n) {
      const int g = idx[i] & 3;
      perm[gstart[g] + c4[g][t] + run[g]] = i;
      run[g]++;
    }
  }
}

// ---- shared transpose body: W [K][N] f32 tile -> WT [N][K] bf16 ----
__device__ __forceinline__ void wtrans_body(
    float (*tile)[65], const float* __restrict__ W, u16* __restrict__ WT,
    int K, int N, int tx, int ty, int o) {
  const float* Wo = W + (size_t)o * K * N;
  u16* WTo = WT + (size_t)o * N * K;
  const int k0 = ty * 64, n0 = tx * 64;
  const int rr = threadIdx.x >> 4, cc = threadIdx.x & 15;
  #pragma unroll
  for (int j = 0; j < 4; ++j) {
    const int r = j * 16 + rr;
    const float4 v = *(const float4*)(Wo + (size_t)(k0 + r) * N + n0 + cc * 4);
    tile[r][cc * 4 + 0] = v.x; tile[r][cc * 4 + 1] = v.y;
    tile[r][cc * 4 + 2] = v.z; tile[r][cc * 4 + 3] = v.w;
  }
  __syncthreads();
  #pragma unroll
  for (int j = 0; j < 4; ++j) {
    const int nrow = j * 16 + rr;
    ushort4 u;
    u.x = f2bf(tile[cc * 4 + 0][nrow]);
    u.y = f2bf(tile[cc * 4 + 1][nrow]);
    u.z = f2bf(tile[cc * 4 + 2][nrow]);
    u.w = f2bf(tile[cc * 4 + 3][nrow]);
    *(ushort4*)(WTo + (size_t)(n0 + nrow) * K + k0 + cc * 4) = u;
  }
}

// ---- k0: W1T transpose (blocks 0..2047) ∥ hist/perm/tmaps (block 2048) ----
// hist is INDEPENDENT of the transposes (no cross-block waits) -> safe under
// undefined dispatch order (Guideline 16).
__global__ __launch_bounds__(256) void w1t_hist_kernel(
    const float* __restrict__ W1, u16* __restrict__ W1T,
    const int* __restrict__ idx, int n, int* __restrict__ starts,
    int* __restrict__ perm, int* __restrict__ tmap64) {
  __shared__ float tile[64][65];   // 16.9 KB, reused as hist scratch
  const int bid = blockIdx.x;
  if (bid == 2048) {  // hist hides under the 48 MB transpose
    hist_body(idx, n, starts, perm, tmap64,
              (int*)&tile[0][0], (int*)&tile[32][0]);
    return;
  }
  const int xcd = bid & 7, i = bid >> 3;
  const int tx = (xcd << 2) | (i & 3);   // consumer-XCD-affine (xcd = tx>>2)
  const int ty = (i >> 2) & 15;
  const int o = i >> 6;
  wtrans_body(tile, W1, W1T, 1024, 2048, tx, ty, o);
}

// ---- k1: gather + f32->bf16 convert into sorted order ----
__global__ __launch_bounds__(256) void gather_kernel(
    const float* __restrict__ x, const int* __restrict__ perm,
    u16* __restrict__ Xs) {
  const int p = blockIdx.x;
  const int b = perm[p];
  const float4 v = ((const float4*)(x + (size_t)b * 1024))[threadIdx.x];
  ushort4 u;
  u.x = f2bf(v.x); u.y = f2bf(v.y); u.z = f2bf(v.z); u.w = f2bf(v.w);
  ((ushort4*)(Xs + (size_t)p * 1024))[threadIdx.x] = u;
}

// ---- grouped GEMM body (R12 structure): tile TM x 128, BK=64, 4 waves,
// 2-buf LDS, counted vmcnt, T2 XOR swizzle, T5 setprio, XCD-chunked swizzle.
// SPLIT: K split count (kb0 = s*KT/SPLIT). EPI 0: bf16 out + bias.
// EPI 1: f32 split-K partial (no bias) at outP[(s*2048+p)*NN+n].
template <int EPI, int TM, int NT_PAD, int KT, int NN, int NTN, int SPLIT>
__device__ __forceinline__ void gemm_body(
    char* smem, int bid,
    const u16* __restrict__ A, const u16* __restrict__ BT,
    const float* __restrict__ bias, const int* __restrict__ starts,
    const int* __restrict__ tmap, float* __restrict__ outP,
    u16* __restrict__ outH) {
  constexpr int MR = TM / 32;
  constexpr int ABUF = TM * 128;
  constexpr int BSTR = ABUF + 16384;

  const int nwg = NT_PAD * NTN * SPLIT;  // % 8 == 0
  const int q = nwg >> 3;
  const int swz = (bid & 7) * q + (bid >> 3);  // XCD-chunked bijective
  const int tile = swz % NT_PAD;               // m fastest: B-panel L2 reuse
  const int rest = swz / NT_PAD;
  const int n_t = rest % NTN;
  const int s = rest / NTN;

  const int tm = tmap[tile];
  if (tm < 0) return;
  const int o = tm >> 28;
  const int m_start = tm & 0x0FFFFFFF;
  const int g1 = starts[o + 1];
  const int n_start = n_t * 128;
  const int kb0 = s * (KT / SPLIT);
  const u16* Bo = BT + (size_t)o * NN * KT;

  const int tid = threadIdx.x;
  const int w = tid >> 6;
  const int l = tid & 63;
  const int wm = w >> 1, wn = w & 1;
  const int l8 = l & 7, ld8 = l >> 3;

  // T2: pre-swizzled global source; linear LDS dest holds swizzled layout
  const int src_unit = l8 ^ (ld8 & 7);

  const u16* pA[MR];
  #pragma unroll
  for (int j = 0; j < MR; ++j) {
    int r = m_start + (j * 4 + w) * 8 + ld8;
    if (r >= g1) r = g1 - 1;
    pA[j] = A + (size_t)r * KT + kb0 + src_unit * 8;
  }
  const u16* pB[4];
  #pragma unroll
  for (int j = 0; j < 4; ++j) {
    const int nr = n_start + (j * 4 + w) * 8 + ld8;
    pB[j] = Bo + (size_t)nr * KT + kb0 + src_unit * 8;
  }

#define STAGE(dst_off)                                                         \
  {                                                                            \
    _Pragma("unroll")                                                          \
    for (int j = 0; j < MR; ++j)                                               \
      __builtin_amdgcn_global_load_lds((as1_cvp)pA[j],                         \
          (as3_vp)(smem + (dst_off) + (j * 4 + w) * 1024), 16, 0, 0);          \
    _Pragma("unroll")                                                          \
    for (int j = 0; j < 4; ++j)                                                \
      __builtin_amdgcn_global_load_lds((as1_cvp)pB[j],                         \
          (as3_vp)(smem + (dst_off) + ABUF + (j * 4 + w) * 1024), 16, 0, 0);   \
    _Pragma("unroll") for (int j = 0; j < MR; ++j) pA[j] += 64;                \
    _Pragma("unroll") for (int j = 0; j < 4; ++j) pB[j] += 64;                 \
  }

  const int lrow = l & 15;
  const int lx = l & 7;
  const int lu = l >> 4;
  int offA[MR][2], offB[4][2];
  #pragma unroll
  for (int a = 0; a < MR; ++a)
    #pragma unroll
    for (int kk = 0; kk < 2; ++kk)
      offA[a][kk] = (wm * (TM / 2) + a * 16 + lrow) * 128 + (((kk * 4 + lu) ^ lx) << 4);
  #pragma unroll
  for (int b = 0; b < 4; ++b)
    #pragma unroll
    for (int kk = 0; kk < 2; ++kk)
      offB[b][kk] = (wn * 64 + b * 16 + lrow) * 128 + (((kk * 4 + lu) ^ lx) << 4);

  f32x4 acc[MR][4] = {};

  const int nK = (KT / SPLIT) >> 6;
  STAGE(0);
  for (int kt = 0; kt < nK; ++kt) {
    const int cur = (kt & 1) * BSTR;
    if (kt + 1 < nK) {
      STAGE(BSTR - cur);
      if constexpr (TM == 128)
        asm volatile("s_waitcnt vmcnt(8)" ::: "memory");
      else
        asm volatile("s_waitcnt vmcnt(6)" ::: "memory");
    } else {
      asm volatile("s_waitcnt vmcnt(0)" ::: "memory");
    }
    __builtin_amdgcn_s_barrier();

    bf16x8 af[MR][2], bfr[4][2];
    #pragma unroll
    for (int a = 0; a < MR; ++a)
      #pragma unroll
      for (int kk = 0; kk < 2; ++kk)
        af[a][kk] = *(const bf16x8*)(smem + cur + offA[a][kk]);
    #pragma unroll
    for (int b = 0; b < 4; ++b)
      #pragma unroll
      for (int kk = 0; kk < 2; ++kk)
        bfr[b][kk] = *(const bf16x8*)(smem + cur + ABUF + offB[b][kk]);
    asm volatile("s_waitcnt lgkmcnt(0)" ::: "memory");
    __builtin_amdgcn_s_barrier();

    __builtin_amdgcn_s_setprio(1);
    #pragma unroll
    for (int kk = 0; kk < 2; ++kk)
      #pragma unroll
      for (int a = 0; a < MR; ++a)
        #pragma unroll
        for (int b = 0; b < 4; ++b)
          acc[a][b] = __builtin_amdgcn_mfma_f32_16x16x32_bf16(af[a][kk], bfr[b][kk], acc[a][b], 0, 0, 0);
    __builtin_amdgcn_s_setprio(0);
  }
#undef STAGE

  // epilogue: C/D layout col = l&15, row = (l>>4)*4 + r  [m89-verified]
  const int col_l = l & 15;
  const int row_l = (l >> 4) << 2;
  #pragma unroll
  for (int a = 0; a < MR; ++a) {
    #pragma unroll
    for (int b = 0; b < 4; ++b) {
      const int n = n_start + wn * 64 + b * 16 + col_l;
      float bv = 0.f;
      if (EPI == 0) bv = bias[n];
      #pragma unroll
      for (int r = 0; r < 4; ++r) {
        const int p = m_start + wm * (TM / 2) + a * 16 + row_l + r;
        if (p < g1) {
          if (EPI == 0) {
            outH[(size_t)p * NN + n] = f2bf(acc[a][b][r] + bv);
          } else {
            outP[((size_t)(s * 2048 + p)) * NN + n] = acc[a][b][r];
          }
        }
      }
    }
  }
}

// ---- k2: GEMM1 TM=64 wide-grid (blocks 0..639) ∥ W2T transpose (640..2687) ----
__global__ __launch_bounds__(256, 3) void gemm1_w2t_kernel(
    const u16* __restrict__ Xs, const u16* __restrict__ W1T,
    const float* __restrict__ b1, const int* __restrict__ starts,
    const int* __restrict__ tmap64, u16* __restrict__ Hs,
    const float* __restrict__ W2, u16* __restrict__ W2T) {
  __shared__ char smem[49152];
  const int bid = blockIdx.x;
  if (bid < 640) {
    gemm_body<0, 64, 40, 1024, 2048, 16, 1>(
        smem, bid, Xs, W1T, b1, starts, tmap64, nullptr, Hs);
  } else {
    // W2: K=2048, N=1024; consumer-XCD-affine (xcd = tx>>1). 640%8==0 so
    // (bid-640)&7 preserves bid&7 XCD parity.
    const int b = bid - 640;
    const int xcd = b & 7, i = b >> 3;
    const int tx = (xcd << 1) | (i & 1);
    const int ty = (i >> 1) & 31;
    const int o = i >> 6;
    wtrans_body((float(*)[65])smem, W2, W2T, 2048, 1024, tx, ty, o);
  }
}

// ---- k3: GEMM2 split-K x2 -> f32 partials (alias dead W1T) ----
__global__ __launch_bounds__(256, 3) void gemm2s_kernel(
    const u16* __restrict__ Hs, const u16* __restrict__ W2T,
    const int* __restrict__ starts, const int* __restrict__ tmap64,
    float* __restrict__ part) {
  __shared__ char smem[49152];
  gemm_body<1, 64, 40, 2048, 1024, 8, 2>(
      smem, blockIdx.x, Hs, W2T, nullptr, starts, tmap64, part, nullptr);
}

// ---- k4: reduce partials + bias + scatter via perm (fixed-order adds) ----
__global__ __launch_bounds__(256) void reduce_kernel(
    const float* __restrict__ part, const float* __restrict__ b2,
    const int* __restrict__ perm, float* __restrict__ out) {
  const int p = blockIdx.x;
  const int t = threadIdx.x;
  const float4 v0 = ((const float4*)(part + (size_t)p * 1024))[t];
  const float4 v1 = ((const float4*)(part + (size_t)(2048 + p) * 1024))[t];
  const float4 bv = ((const float4*)b2)[t];
  float4 r;
  r.x = v0.x + v1.x + bv.x;
  r.y = v0.y + v1.y + bv.y;
  r.z = v0.z + v1.z + bv.z;
  r.w = v0.w + v1.w + bv.w;
  ((float4*)(out + (size_t)perm[p] * 1024))[t] = r;
}

extern "C" void kernel_launch(void* const* d_in, const int* in_sizes, int n_in,
                              void* d_out, int out_size, void* d_ws, size_t ws_size,
                              hipStream_t stream) {
  (void)n_in; (void)out_size; (void)ws_size;
  const float* x   = (const float*)d_in[0];
  const int*   idx = (const int*)d_in[1];
  const float* W1  = (const float*)d_in[2];
  const float* b1  = (const float*)d_in[3];
  const float* W2  = (const float*)d_in[4];
  const float* b2  = (const float*)d_in[5];
  float* out = (float*)d_out;

  const int B = in_sizes[1];  // 2048

  // workspace layout (~44.06 MB; part aliases W1T, dead after GEMM1)
  char* ws = (char*)d_ws;
  u16* W1T     = (u16*)(ws);                    // 16 MB [o][N=2048][K=1024]
  float* part  = (float*)(ws);                  // 2*2048*1024 f32 = 16 MB alias
  u16* W2T     = (u16*)(ws + 16777216);         // 16 MB [o][N=1024][K=2048]
  u16* Xs      = (u16*)(ws + 33554432);         // B*1024 bf16 = 4 MB (sorted)
  u16* Hs      = (u16*)(ws + 37748736);         // B*2048 bf16 = 8 MB (sorted)
  int* perm    = (int*)(ws + 46137344);         // B ints
  int* starts  = (int*)(ws + 46137344 + 8192);  // 5 ints
  int* tmap64  = starts + 128;                  // 40 ints

  // k0: W1T transpose ∥ hist (hist's ~2.5 µs hides under 48 MB transpose)
  w1t_hist_kernel<<<2049, 256, 0, stream>>>(W1, W1T, idx, B, starts, perm,
                                            tmap64);
  // k1: gather x rows into sorted bf16 Xs
  gather_kernel<<<B, 256, 0, stream>>>(x, perm, Xs);
  // k2: GEMM1 (TM=64, 640 blocks x 16 K-steps) ∥ W2T transpose
  gemm1_w2t_kernel<<<640 + 2048, 256, 0, stream>>>(
      Xs, W1T, b1, starts, tmap64, Hs, W2, W2T);
  // k3: GEMM2 split-K x2 (640 blocks, 16 K-steps each) -> partials
  gemm2s_kernel<<<640, 256, 0, stream>>>(Hs, W2T, starts, tmap64, part);
  // k4: reduce + b2 + scatter
  reduce_kernel<<<B, 256, 0, stream>>>(part, b2, perm, out);
}